// Round 1
// baseline (949.960 us; speedup 1.0000x reference)
//
#include <hip/hip_runtime.h>
#include <hip/hip_bf16.h>

typedef __bf16 bf16_t;
typedef __bf16 bf16x8 __attribute__((ext_vector_type(8)));
typedef float f32x4 __attribute__((ext_vector_type(4)));

typedef __attribute__((address_space(1))) unsigned int as1_uint;
typedef __attribute__((address_space(3))) unsigned int as3_uint;

#define Bsz 4
#define Ssz 2048
#define Dsz 1024
#define BSD (Bsz * Ssz * Dsz)   /* 8388608 */
#define SCALE_ 0.03125f          /* 1/sqrt(1024) */

__device__ __forceinline__ void gll16(const void* g, void* l) {
  __builtin_amdgcn_global_load_lds((const as1_uint*)g, (as3_uint*)l, 16, 0, 0);
}

// ---------------------------------------------------------------------------
// GEMM core: one 128x128 C tile.  A row-major (lda), Bt row-major (N,K) (ldb).
// K tiled by 64.  A source switches to A2 at k-tile ksplit (for concat GEMM).
// LDS layout: row r (0..127) x chunk slot s (0..7, 16B chunks), slot = c ^ (r&7)
// (XOR swizzle keeps ds_read_b128 conflict-free while staying lane-linear for
// global_load_lds).
// ---------------------------------------------------------------------------
__device__ __forceinline__ void gemm_core(const bf16_t* A, const bf16_t* A2, int ksplit,
                                          int lda, int lda2,
                                          const bf16_t* Bt, int ldb,
                                          int ktiles, f32x4 acc[4][4]) {
  __shared__ __attribute__((aligned(16))) bf16_t As[128 * 64];
  __shared__ __attribute__((aligned(16))) bf16_t Bs[128 * 64];
  const int tid = threadIdx.x;
  const int wave = tid >> 6, lane = tid & 63;
  const int quad = lane >> 4, m16 = lane & 15, x7 = lane & 7;
  const int waveM = (wave >> 1) << 6, waveN = (wave & 1) << 6;
  const int srow = tid >> 3;                              // 0..31
  const int schunk = (tid & 7) ^ ((tid >> 3) & 7);        // swizzled global chunk
  char* AsB = (char*)As;
  char* BsB = (char*)Bs;
  const int ldsbase = wave << 10;

  for (int kt = 0; kt < ktiles; ++kt) {
    const bf16_t* Ak = (kt < ksplit) ? (A + kt * 64) : (A2 + (kt - ksplit) * 64);
    const int ldak = (kt < ksplit) ? lda : lda2;
    const bf16_t* Bk = Bt + kt * 64;
    __syncthreads();
#pragma unroll
    for (int it = 0; it < 4; ++it)
      gll16(Ak + (size_t)(it * 32 + srow) * ldak + schunk * 8, AsB + it * 4096 + ldsbase);
#pragma unroll
    for (int it = 0; it < 4; ++it)
      gll16(Bk + (size_t)(it * 32 + srow) * ldb + schunk * 8, BsB + it * 4096 + ldsbase);
    __syncthreads();
#pragma unroll
    for (int t = 0; t < 2; ++t) {
      bf16x8 a[4], b[4];
      const int cc = t * 4 + quad;
#pragma unroll
      for (int i = 0; i < 4; ++i) {
        const int rr = waveM + i * 16 + m16;
        a[i] = *(const bf16x8*)(AsB + rr * 128 + ((cc ^ x7) << 4));
      }
#pragma unroll
      for (int j = 0; j < 4; ++j) {
        const int rr = waveN + j * 16 + m16;
        b[j] = *(const bf16x8*)(BsB + rr * 128 + ((cc ^ x7) << 4));
      }
#pragma unroll
      for (int i = 0; i < 4; ++i)
#pragma unroll
        for (int j = 0; j < 4; ++j)
          acc[i][j] = __builtin_amdgcn_mfma_f32_16x16x32_bf16(a[i], b[j], acc[i][j], 0, 0, 0);
    }
  }
}

// Generic batched bt-GEMM, bf16 out, optional fp32 bias, optional B-batch roll.
__global__ __launch_bounds__(256, 2)
void gemm_bt_bf16(const bf16_t* __restrict__ A, long long sAz, int lda,
                  const bf16_t* __restrict__ Bt, long long sBz, int ldb,
                  const float* __restrict__ bias, int sbz,
                  bf16_t* __restrict__ C, long long sCz, int ldc,
                  int K, int rollB) {
  const int z = blockIdx.z;
  int zb = z;
  if (rollB) { const int m = z >> 2, b = z & 3; zb = ((m + 1) % 3) * Bsz + b; }
  const bf16_t* Az = A + (long long)z * sAz + (size_t)blockIdx.y * 128 * lda;
  const bf16_t* Bz = Bt + (long long)zb * sBz + (size_t)blockIdx.x * 128 * ldb;
  f32x4 acc[4][4];
  const f32x4 zero = {0.f, 0.f, 0.f, 0.f};
#pragma unroll
  for (int i = 0; i < 4; ++i)
#pragma unroll
    for (int j = 0; j < 4; ++j) acc[i][j] = zero;

  gemm_core(Az, Az, 1 << 30, lda, lda, Bz, ldb, K / 64, acc);

  const int lane = threadIdx.x & 63, wave = threadIdx.x >> 6;
  const int m0 = blockIdx.y * 128 + ((wave >> 1) << 6) + ((lane >> 4) << 2);
  const int n0 = blockIdx.x * 128 + ((wave & 1) << 6) + (lane & 15);
  bf16_t* Cz = C + (long long)z * sCz;
  const float* bz = bias ? (bias + (long long)z * sbz) : nullptr;
#pragma unroll
  for (int j = 0; j < 4; ++j) {
    const int col = n0 + j * 16;
    const float bv = bz ? bz[col] : 0.0f;
#pragma unroll
    for (int i = 0; i < 4; ++i) {
      const int row = m0 + i * 16;
#pragma unroll
      for (int r = 0; r < 4; ++r)
        Cz[(size_t)(row + r) * ldc + col] = (bf16_t)(acc[i][j][r] + bv);
    }
  }
}

// Final projection: comb = [x | ctx] (k-split A), Wo^T, +bo, dual fp32 store.
__global__ __launch_bounds__(256, 2)
void gemm_out(const bf16_t* __restrict__ xb, const bf16_t* __restrict__ ctx,
              const bf16_t* __restrict__ Wot, const float* __restrict__ bo,
              float* __restrict__ out) {
  const int m = blockIdx.z;
  const bf16_t* Az = xb + (long long)m * BSD + (size_t)blockIdx.y * 128 * Dsz;
  const bf16_t* A2z = ctx + (long long)m * BSD + (size_t)blockIdx.y * 128 * Dsz;
  const bf16_t* Bz = Wot + (long long)m * (Dsz * 2 * Dsz) + (size_t)blockIdx.x * 128 * (2 * Dsz);
  f32x4 acc[4][4];
  const f32x4 zero = {0.f, 0.f, 0.f, 0.f};
#pragma unroll
  for (int i = 0; i < 4; ++i)
#pragma unroll
    for (int j = 0; j < 4; ++j) acc[i][j] = zero;

  gemm_core(Az, A2z, 16, Dsz, Dsz, Bz, 2 * Dsz, 32, acc);

  const int lane = threadIdx.x & 63, wave = threadIdx.x >> 6;
  const int m0 = blockIdx.y * 128 + ((wave >> 1) << 6) + ((lane >> 4) << 2);
  const int n0 = blockIdx.x * 128 + ((wave & 1) << 6) + (lane & 15);
  const float* bz = bo + m * Dsz;
#pragma unroll
  for (int j = 0; j < 4; ++j) {
    const int col = n0 + j * 16;
    const float bv = bz[col];
#pragma unroll
    for (int i = 0; i < 4; ++i) {
#pragma unroll
      for (int r = 0; r < 4; ++r) {
        const int row = m0 + i * 16 + r;
        const float v = acc[i][j][r] + bv;
        const int b = row >> 11, s = row & 2047;
        out[(size_t)m * BSD + (size_t)row * Dsz + col] = v;
        out[(size_t)3 * BSD + (size_t)b * (3 * Ssz * Dsz) + (size_t)(m * Ssz + s) * Dsz + col] = v;
      }
    }
  }
}

// x1,x2,x3 fp32 -> xb bf16 (3,B,S,D)
__global__ __launch_bounds__(256)
void cvt_x(const float* __restrict__ x1, const float* __restrict__ x2,
           const float* __restrict__ x3, bf16_t* __restrict__ xb) {
  const size_t i = ((size_t)blockIdx.x * 256 + threadIdx.x) * 4;
  const float* src;
  size_t off;
  if (i < (size_t)BSD)          { src = x1; off = i; }
  else if (i < (size_t)2 * BSD) { src = x2; off = i - BSD; }
  else                          { src = x3; off = i - (size_t)2 * BSD; }
  const float4 v = *(const float4*)(src + off);
  union { bf16_t h[4]; uint2 u; } o;
  o.h[0] = (bf16_t)v.x; o.h[1] = (bf16_t)v.y; o.h[2] = (bf16_t)v.z; o.h[3] = (bf16_t)v.w;
  *(uint2*)(xb + i) = o.u;
}

// Transpose (R,C)->(C,R), convert to bf16.  64x64 tiles.
template <typename TIN>
__global__ __launch_bounds__(256)
void transpose_to_bf16(const TIN* __restrict__ in, bf16_t* __restrict__ out,
                       int ldin, int ldout, long long sIn, long long sOut) {
  __shared__ bf16_t Ts[64][65];
  const int t = threadIdx.x;
  const long long z = blockIdx.z;
  const TIN* inz = in + z * sIn;
  bf16_t* outz = out + z * sOut;
  const int r0 = blockIdx.y << 6, c0 = blockIdx.x << 6;
#pragma unroll
  for (int e = 0; e < 4; ++e) {
    const int idx = (e * 256 + t) * 4;
    const int rr = idx >> 6, cc = idx & 63;
    const TIN* p = inz + (size_t)(r0 + rr) * ldin + (c0 + cc);
    if constexpr (sizeof(TIN) == 4) {
      const float4 v = *(const float4*)p;
      Ts[rr][cc] = (bf16_t)v.x; Ts[rr][cc + 1] = (bf16_t)v.y;
      Ts[rr][cc + 2] = (bf16_t)v.z; Ts[rr][cc + 3] = (bf16_t)v.w;
    } else {
      union { bf16_t h[4]; uint2 u; } tmp;
      tmp.u = *(const uint2*)p;
      Ts[rr][cc] = tmp.h[0]; Ts[rr][cc + 1] = tmp.h[1];
      Ts[rr][cc + 2] = tmp.h[2]; Ts[rr][cc + 3] = tmp.h[3];
    }
  }
  __syncthreads();
#pragma unroll
  for (int e = 0; e < 4; ++e) {
    const int idx = (e * 256 + t) * 4;
    const int oc = idx >> 6, orr = idx & 63;
    union { bf16_t h[4]; uint2 u; } o4;
    o4.h[0] = Ts[orr][oc]; o4.h[1] = Ts[orr + 1][oc];
    o4.h[2] = Ts[orr + 2][oc]; o4.h[3] = Ts[orr + 3][oc];
    *(uint2*)(outz + (size_t)(c0 + oc) * ldout + (r0 + orr)) = o4.u;
  }
}

__device__ __forceinline__ unsigned bfbits(float f) {
  union { bf16_t h; unsigned short u; } c;
  c.h = (bf16_t)f;
  return (unsigned)c.u;
}

// Row softmax (with scale folded in), in place, bf16, rows of length 2048.
__global__ __launch_bounds__(256)
void softmax_rows(bf16_t* __restrict__ Sc) {
  const size_t row = blockIdx.x;
  uint4* p = (uint4*)(Sc + row * Ssz);
  const int t = threadIdx.x;
  const int lane = t & 63, wave = t >> 6;
  uint4 u = p[t];
  float v[8];
  v[0] = __uint_as_float(u.x << 16); v[1] = __uint_as_float(u.x & 0xffff0000u);
  v[2] = __uint_as_float(u.y << 16); v[3] = __uint_as_float(u.y & 0xffff0000u);
  v[4] = __uint_as_float(u.z << 16); v[5] = __uint_as_float(u.z & 0xffff0000u);
  v[6] = __uint_as_float(u.w << 16); v[7] = __uint_as_float(u.w & 0xffff0000u);

  float mx = v[0];
#pragma unroll
  for (int i = 1; i < 8; ++i) mx = fmaxf(mx, v[i]);
  for (int o = 32; o > 0; o >>= 1) mx = fmaxf(mx, __shfl_xor(mx, o));
  __shared__ float redm[4], reds[4];
  if (lane == 0) redm[wave] = mx;
  __syncthreads();
  mx = fmaxf(fmaxf(redm[0], redm[1]), fmaxf(redm[2], redm[3]));

  float s = 0.f;
#pragma unroll
  for (int i = 0; i < 8; ++i) { v[i] = __expf((v[i] - mx) * SCALE_); s += v[i]; }
  for (int o = 32; o > 0; o >>= 1) s += __shfl_xor(s, o);
  if (lane == 0) reds[wave] = s;
  __syncthreads();
  s = reds[0] + reds[1] + reds[2] + reds[3];
  const float inv = 1.0f / s;
#pragma unroll
  for (int i = 0; i < 8; ++i) v[i] *= inv;

  u.x = bfbits(v[0]) | (bfbits(v[1]) << 16);
  u.y = bfbits(v[2]) | (bfbits(v[3]) << 16);
  u.z = bfbits(v[4]) | (bfbits(v[5]) << 16);
  u.w = bfbits(v[6]) | (bfbits(v[7]) << 16);
  p[t] = u;
}

extern "C" void kernel_launch(void* const* d_in, const int* in_sizes, int n_in,
                              void* d_out, int out_size, void* d_ws, size_t ws_size,
                              hipStream_t stream) {
  const float* x1 = (const float*)d_in[0];
  const float* x2 = (const float*)d_in[1];
  const float* x3 = (const float*)d_in[2];
  const float* Wq = (const float*)d_in[3];
  const float* bq = (const float*)d_in[4];
  const float* Wk = (const float*)d_in[5];
  const float* bk = (const float*)d_in[6];
  const float* Wv = (const float*)d_in[7];
  const float* bv = (const float*)d_in[8];
  const float* Wo = (const float*)d_in[9];
  const float* bo = (const float*)d_in[10];

  char* ws = (char*)d_ws;
  bf16_t* xb  = (bf16_t*)(ws + 0);           // 50,331,648 B
  bf16_t* Wqt = (bf16_t*)(ws + 50331648);    //  6,291,456 B
  bf16_t* Wkt = (bf16_t*)(ws + 56623104);
  bf16_t* Wvt = (bf16_t*)(ws + 62914560);
  bf16_t* Wot = (bf16_t*)(ws + 69206016);    // 12,582,912 B
  bf16_t* Q   = (bf16_t*)(ws + 81788928);    // 50,331,648 B
  bf16_t* Kb  = (bf16_t*)(ws + 132120576);   // 50,331,648 B
  bf16_t* V   = (bf16_t*)(ws + 182452224);   // 50,331,648 B  (total 232,783,872)
  bf16_t* Sc  = (bf16_t*)d_out;              // scores scratch lives in d_out (100.7 MB <= 201 MB)
  bf16_t* Vt  = Q;                           // alias: Q dead after scores GEMM
  bf16_t* ctx = Kb;                          // alias: K dead after scores GEMM

  // 1) x -> bf16
  cvt_x<<<24576, 256, 0, stream>>>(x1, x2, x3, xb);
  // 2) weights -> bf16, transposed to (N,K)
  transpose_to_bf16<float><<<dim3(16, 16, 3), 256, 0, stream>>>(Wq, Wqt, 1024, 1024, 1048576LL, 1048576LL);
  transpose_to_bf16<float><<<dim3(16, 16, 3), 256, 0, stream>>>(Wk, Wkt, 1024, 1024, 1048576LL, 1048576LL);
  transpose_to_bf16<float><<<dim3(16, 16, 3), 256, 0, stream>>>(Wv, Wvt, 1024, 1024, 1048576LL, 1048576LL);
  transpose_to_bf16<float><<<dim3(16, 32, 3), 256, 0, stream>>>(Wo, Wot, 1024, 2048, 2097152LL, 2097152LL);
  // 3) Q/K/V projections (+bias)
  const dim3 gqkv(8, 64, 3);
  gemm_bt_bf16<<<gqkv, 256, 0, stream>>>(xb, (long long)BSD, Dsz, Wqt, 1048576LL, Dsz, bq, Dsz, Q,  (long long)BSD, Dsz, Dsz, 0);
  gemm_bt_bf16<<<gqkv, 256, 0, stream>>>(xb, (long long)BSD, Dsz, Wkt, 1048576LL, Dsz, bk, Dsz, Kb, (long long)BSD, Dsz, Dsz, 0);
  gemm_bt_bf16<<<gqkv, 256, 0, stream>>>(xb, (long long)BSD, Dsz, Wvt, 1048576LL, Dsz, bv, Dsz, V,  (long long)BSD, Dsz, Dsz, 0);
  // 4) scores = Q K^T  (scale folded into softmax)
  gemm_bt_bf16<<<dim3(16, 16, 12), 256, 0, stream>>>(Q, 2097152LL, Dsz, Kb, 2097152LL, Dsz, nullptr, 0, Sc, 4194304LL, Ssz, Dsz, 0);
  // 5) softmax rows (in place)
  softmax_rows<<<24576, 256, 0, stream>>>(Sc);
  // 6) V -> V^T (per (m,b) slab)
  transpose_to_bf16<bf16_t><<<dim3(16, 32, 12), 256, 0, stream>>>(V, Vt, 1024, 2048, 2097152LL, 2097152LL);
  // 7) ctx = P @ V_{(m+1)%3}
  gemm_bt_bf16<<<dim3(8, 16, 12), 256, 0, stream>>>(Sc, 4194304LL, Ssz, Vt, 2097152LL, Ssz, nullptr, 0, ctx, 2097152LL, Dsz, Ssz, 1);
  // 8) out = [x|ctx] @ Wo + bo  -> fp32 d_out (out_m and global_feature)
  gemm_out<<<dim3(8, 64, 3), 256, 0, stream>>>(xb, ctx, Wot, bo, (float*)d_out);
}

// Round 2
// 871.891 us; speedup vs baseline: 1.0895x; 1.0895x over previous
//
#include <hip/hip_runtime.h>
#include <hip/hip_bf16.h>

typedef __bf16 bf16_t;
typedef __bf16 bf16x8 __attribute__((ext_vector_type(8)));
typedef float f32x4 __attribute__((ext_vector_type(4)));

typedef __attribute__((address_space(1))) unsigned int as1_uint;
typedef __attribute__((address_space(3))) unsigned int as3_uint;

#define Bsz 4
#define Ssz 2048
#define Dsz 1024
#define BSD (Bsz * Ssz * Dsz)   /* 8388608 */
#define SCALE_ 0.03125f         /* 1/sqrt(1024) */

__device__ __forceinline__ void gll16(const void* g, void* l) {
  __builtin_amdgcn_global_load_lds((const as1_uint*)g, (as3_uint*)l, 16, 0, 0);
}

__device__ __forceinline__ unsigned bfbits(float f) {
  union { bf16_t h; unsigned short u; } c;
  c.h = (bf16_t)f;
  return (unsigned)c.u;
}

// ---------------------------------------------------------------------------
// GEMM core, OPERAND-SWAPPED: acc[i][j] = mfma(b[j], a[i], acc) so that the
// C/D fragment holds, per lane: M = tile + i*16 + (lane&15)  (fixed per i),
//                               N = tile + j*16 + (lane>>4)*4 + reg (4 consec).
// -> epilogue stores are 4-element vectors along N.
// A row-major (lda), Bt row-major (N,K) (ldb). K tiled by 64; A switches to A2
// at k-tile ksplit (for the concat GEMM).  XOR-swizzled LDS, gll16 staging.
// ---------------------------------------------------------------------------
__device__ __forceinline__ void gemm_core(char* AsB, char* BsB,
                                          const bf16_t* A, const bf16_t* A2, int ksplit,
                                          int lda, int lda2,
                                          const bf16_t* Bt, int ldb,
                                          int ktiles, f32x4 acc[4][4]) {
  const int tid = threadIdx.x;
  const int wave = tid >> 6, lane = tid & 63;
  const int quad = lane >> 4, m16 = lane & 15, x7 = lane & 7;
  const int waveM = (wave >> 1) << 6, waveN = (wave & 1) << 6;
  const int srow = tid >> 3;                              // 0..31
  const int schunk = (tid & 7) ^ ((tid >> 3) & 7);        // swizzled global chunk
  const int ldsbase = wave << 10;

  for (int kt = 0; kt < ktiles; ++kt) {
    const bf16_t* Ak = (kt < ksplit) ? (A + kt * 64) : (A2 + (kt - ksplit) * 64);
    const int ldak = (kt < ksplit) ? lda : lda2;
    const bf16_t* Bk = Bt + kt * 64;
    __syncthreads();
#pragma unroll
    for (int it = 0; it < 4; ++it)
      gll16(Ak + (size_t)(it * 32 + srow) * ldak + schunk * 8, AsB + it * 4096 + ldsbase);
#pragma unroll
    for (int it = 0; it < 4; ++it)
      gll16(Bk + (size_t)(it * 32 + srow) * ldb + schunk * 8, BsB + it * 4096 + ldsbase);
    __syncthreads();
#pragma unroll
    for (int t = 0; t < 2; ++t) {
      bf16x8 a[4], b[4];
      const int cc = t * 4 + quad;
#pragma unroll
      for (int i = 0; i < 4; ++i) {
        const int rr = waveM + i * 16 + m16;
        a[i] = *(const bf16x8*)(AsB + rr * 128 + ((cc ^ x7) << 4));
      }
#pragma unroll
      for (int j = 0; j < 4; ++j) {
        const int rr = waveN + j * 16 + m16;
        b[j] = *(const bf16x8*)(BsB + rr * 128 + ((cc ^ x7) << 4));
      }
#pragma unroll
      for (int i = 0; i < 4; ++i)
#pragma unroll
        for (int j = 0; j < 4; ++j)
          acc[i][j] = __builtin_amdgcn_mfma_f32_16x16x32_bf16(b[j], a[i], acc[i][j], 0, 0, 0);
    }
  }
}

__device__ __forceinline__ ushort4 pack4(const f32x4 v, const float4 b) {
  ushort4 u;
  u.x = (unsigned short)bfbits(v[0] + b.x);
  u.y = (unsigned short)bfbits(v[1] + b.y);
  u.z = (unsigned short)bfbits(v[2] + b.z);
  u.w = (unsigned short)bfbits(v[3] + b.w);
  return u;
}

// Generic batched bt-GEMM, bf16 out (vector stores), optional B-batch roll.
__global__ __launch_bounds__(256, 2)
void gemm_bt_bf16(const bf16_t* __restrict__ A, long long sAz, int lda,
                  const bf16_t* __restrict__ Bt, long long sBz, int ldb,
                  bf16_t* __restrict__ C, long long sCz, int ldc,
                  int K, int rollB) {
  __shared__ __attribute__((aligned(16))) char smem[32768];
  const int z = blockIdx.z;
  int zb = z;
  if (rollB) { const int m = z >> 2, b = z & 3; zb = ((m + 1) % 3) * Bsz + b; }
  const bf16_t* Az = A + (long long)z * sAz + (size_t)blockIdx.y * 128 * lda;
  const bf16_t* Bz = Bt + (long long)zb * sBz + (size_t)blockIdx.x * 128 * ldb;
  f32x4 acc[4][4];
  const f32x4 zero = {0.f, 0.f, 0.f, 0.f};
#pragma unroll
  for (int i = 0; i < 4; ++i)
#pragma unroll
    for (int j = 0; j < 4; ++j) acc[i][j] = zero;

  gemm_core(smem, smem + 16384, Az, Az, 1 << 30, lda, lda, Bz, ldb, K / 64, acc);

  const int lane = threadIdx.x & 63, wave = threadIdx.x >> 6;
  const int Mb = blockIdx.y * 128 + ((wave >> 1) << 6) + (lane & 15);
  const int Nb = blockIdx.x * 128 + ((wave & 1) << 6) + ((lane >> 4) << 2);
  bf16_t* Cz = C + (long long)z * sCz;
  const float4 zb4 = {0.f, 0.f, 0.f, 0.f};
#pragma unroll
  for (int i = 0; i < 4; ++i) {
    const int M = Mb + i * 16;
#pragma unroll
    for (int j = 0; j < 4; ++j) {
      const int N = Nb + j * 16;
      *(ushort4*)(Cz + (size_t)M * ldc + N) = pack4(acc[i][j], zb4);
    }
  }
}

// Fused QKV projection: B = packed [Wq;Wk;Wv]^T (3072,1024) per modality.
// which = x>>3 selects segment; V segment is written TRANSPOSED (d,t) via an
// LDS tile transpose (row stride 264B keeps ds writes conflict-free).
__global__ __launch_bounds__(256, 2)
void gemm_qkv(const bf16_t* __restrict__ xb, const bf16_t* __restrict__ Wqkvt,
              const float* __restrict__ bq, const float* __restrict__ bk,
              const float* __restrict__ bvp,
              bf16_t* __restrict__ Q, bf16_t* __restrict__ Kb, bf16_t* __restrict__ Vt) {
  __shared__ __attribute__((aligned(16))) char smem[34048];
  const int m = blockIdx.z;
  const int x = blockIdx.x;
  const int which = x >> 3;
  const bf16_t* Az = xb + (size_t)m * BSD + (size_t)blockIdx.y * 128 * Dsz;
  const bf16_t* Bz = Wqkvt + (size_t)m * 3145728 + (size_t)x * 131072;
  f32x4 acc[4][4];
  const f32x4 zero = {0.f, 0.f, 0.f, 0.f};
#pragma unroll
  for (int i = 0; i < 4; ++i)
#pragma unroll
    for (int j = 0; j < 4; ++j) acc[i][j] = zero;

  gemm_core(smem, smem + 16384, Az, Az, 1 << 30, Dsz, Dsz, Bz, Dsz, 16, acc);

  const int tid = threadIdx.x;
  const int lane = tid & 63, wave = tid >> 6;
  const int Ml = ((wave >> 1) << 6) + (lane & 15);       // local M (+i*16)
  const int Nl = ((wave & 1) << 6) + ((lane >> 4) << 2); // local N (+j*16)
  const int dseg0 = (x & 7) * 128;
  const float* bb = (which == 0 ? bq : which == 1 ? bk : bvp) + m * Dsz;

  if (which < 2) {
    bf16_t* Cz = (which == 0 ? Q : Kb) + (size_t)m * BSD;
#pragma unroll
    for (int j = 0; j < 4; ++j) {
      const int N = Nl + j * 16;
      const float4 b4 = *(const float4*)(bb + dseg0 + N);
#pragma unroll
      for (int i = 0; i < 4; ++i) {
        const int M = blockIdx.y * 128 + Ml + i * 16;
        *(ushort4*)(Cz + (size_t)M * Dsz + dseg0 + N) = pack4(acc[i][j], b4);
      }
    }
  } else {
    unsigned short* T = (unsigned short*)smem;           // [128][132] elems (264B rows)
    __syncthreads();
#pragma unroll
    for (int j = 0; j < 4; ++j) {
      const int N = Nl + j * 16;
      const float4 b4 = *(const float4*)(bb + dseg0 + N);
      const float bia[4] = {b4.x, b4.y, b4.z, b4.w};
#pragma unroll
      for (int i = 0; i < 4; ++i) {
        const int M = Ml + i * 16;
#pragma unroll
        for (int r = 0; r < 4; ++r)
          T[(N + r) * 132 + M] = (unsigned short)bfbits(acc[i][j][r] + bia[r]);
      }
    }
    __syncthreads();
    const int b = blockIdx.y >> 4;
    const int s0 = (blockIdx.y & 15) * 128;
    bf16_t* Vz = Vt + ((size_t)(m * 4 + b) * 1024 + dseg0) * Ssz;
#pragma unroll
    for (int e = 0; e < 16; ++e) {
      const int idx = e * 256 + tid;
      const int nl = idx >> 5, mc = (idx & 31) * 4;
      const ushort4 u = *(const ushort4*)(T + nl * 132 + mc);
      *(ushort4*)(Vz + (size_t)nl * Ssz + s0 + mc) = u;
    }
  }
}

// Final projection: comb = [x | ctx] (k-split A), Wo^T, +bo, dual fp32 store.
__global__ __launch_bounds__(256, 2)
void gemm_out(const bf16_t* __restrict__ xb, const bf16_t* __restrict__ ctx,
              const bf16_t* __restrict__ Wot, const float* __restrict__ bo,
              float* __restrict__ out) {
  __shared__ __attribute__((aligned(16))) char smem[32768];
  const int m = blockIdx.z;
  const bf16_t* Az = xb + (size_t)m * BSD + (size_t)blockIdx.y * 128 * Dsz;
  const bf16_t* A2z = ctx + (size_t)m * BSD + (size_t)blockIdx.y * 128 * Dsz;
  const bf16_t* Bz = Wot + (size_t)m * (Dsz * 2 * Dsz) + (size_t)blockIdx.x * 128 * (2 * Dsz);
  f32x4 acc[4][4];
  const f32x4 zero = {0.f, 0.f, 0.f, 0.f};
#pragma unroll
  for (int i = 0; i < 4; ++i)
#pragma unroll
    for (int j = 0; j < 4; ++j) acc[i][j] = zero;

  gemm_core(smem, smem + 16384, Az, A2z, 16, Dsz, Dsz, Bz, 2 * Dsz, 32, acc);

  const int lane = threadIdx.x & 63, wave = threadIdx.x >> 6;
  const int Mb = blockIdx.y * 128 + ((wave >> 1) << 6) + (lane & 15);
  const int Nb = blockIdx.x * 128 + ((wave & 1) << 6) + ((lane >> 4) << 2);
  const float* bz = bo + m * Dsz;
#pragma unroll
  for (int i = 0; i < 4; ++i) {
    const int M = Mb + i * 16;
    const int b = M >> 11, s = M & 2047;
    float* o1 = out + (size_t)m * BSD + (size_t)M * Dsz;
    float* o2 = out + (size_t)3 * BSD + (size_t)b * (3 * Ssz * Dsz) + (size_t)(m * Ssz + s) * Dsz;
#pragma unroll
    for (int j = 0; j < 4; ++j) {
      const int N = Nb + j * 16;
      const float4 b4 = *(const float4*)(bz + N);
      float4 o;
      o.x = acc[i][j][0] + b4.x; o.y = acc[i][j][1] + b4.y;
      o.z = acc[i][j][2] + b4.z; o.w = acc[i][j][3] + b4.w;
      *(float4*)(o1 + N) = o;
      *(float4*)(o2 + N) = o;
    }
  }
}

// x1,x2,x3 fp32 -> xb bf16 (3,B,S,D)
__global__ __launch_bounds__(256)
void cvt_x(const float* __restrict__ x1, const float* __restrict__ x2,
           const float* __restrict__ x3, bf16_t* __restrict__ xb) {
  const size_t i = ((size_t)blockIdx.x * 256 + threadIdx.x) * 4;
  const float* src;
  size_t off;
  if (i < (size_t)BSD)          { src = x1; off = i; }
  else if (i < (size_t)2 * BSD) { src = x2; off = i - BSD; }
  else                          { src = x3; off = i - (size_t)2 * BSD; }
  const float4 v = *(const float4*)(src + off);
  union { bf16_t h[4]; uint2 u; } o;
  o.h[0] = (bf16_t)v.x; o.h[1] = (bf16_t)v.y; o.h[2] = (bf16_t)v.z; o.h[3] = (bf16_t)v.w;
  *(uint2*)(xb + i) = o.u;
}

// Transpose (R,C)->(C,R), convert fp32 to bf16.  64x64 tiles.
__global__ __launch_bounds__(256)
void transpose_to_bf16(const float* __restrict__ in, bf16_t* __restrict__ out,
                       int ldin, int ldout, long long sIn, long long sOut) {
  __shared__ bf16_t Ts[64][65];
  const int t = threadIdx.x;
  const long long z = blockIdx.z;
  const float* inz = in + z * sIn;
  bf16_t* outz = out + z * sOut;
  const int r0 = blockIdx.y << 6, c0 = blockIdx.x << 6;
#pragma unroll
  for (int e = 0; e < 4; ++e) {
    const int idx = (e * 256 + t) * 4;
    const int rr = idx >> 6, cc = idx & 63;
    const float4 v = *(const float4*)(inz + (size_t)(r0 + rr) * ldin + (c0 + cc));
    Ts[rr][cc] = (bf16_t)v.x; Ts[rr][cc + 1] = (bf16_t)v.y;
    Ts[rr][cc + 2] = (bf16_t)v.z; Ts[rr][cc + 3] = (bf16_t)v.w;
  }
  __syncthreads();
#pragma unroll
  for (int e = 0; e < 4; ++e) {
    const int idx = (e * 256 + t) * 4;
    const int oc = idx >> 6, orr = idx & 63;
    union { bf16_t h[4]; uint2 u; } o4;
    o4.h[0] = Ts[orr][oc]; o4.h[1] = Ts[orr + 1][oc];
    o4.h[2] = Ts[orr + 2][oc]; o4.h[3] = Ts[orr + 3][oc];
    *(uint2*)(outz + (size_t)(c0 + oc) * ldout + (r0 + orr)) = o4.u;
  }
}

// Row softmax (scale folded in), in place, bf16, rows of length 2048.
__global__ __launch_bounds__(256)
void softmax_rows(bf16_t* __restrict__ Sc) {
  const size_t row = blockIdx.x;
  uint4* p = (uint4*)(Sc + row * Ssz);
  const int t = threadIdx.x;
  const int lane = t & 63, wave = t >> 6;
  uint4 u = p[t];
  float v[8];
  v[0] = __uint_as_float(u.x << 16); v[1] = __uint_as_float(u.x & 0xffff0000u);
  v[2] = __uint_as_float(u.y << 16); v[3] = __uint_as_float(u.y & 0xffff0000u);
  v[4] = __uint_as_float(u.z << 16); v[5] = __uint_as_float(u.z & 0xffff0000u);
  v[6] = __uint_as_float(u.w << 16); v[7] = __uint_as_float(u.w & 0xffff0000u);

  float mx = v[0];
#pragma unroll
  for (int i = 1; i < 8; ++i) mx = fmaxf(mx, v[i]);
  for (int o = 32; o > 0; o >>= 1) mx = fmaxf(mx, __shfl_xor(mx, o));
  __shared__ float redm[4], reds[4];
  if (lane == 0) redm[wave] = mx;
  __syncthreads();
  mx = fmaxf(fmaxf(redm[0], redm[1]), fmaxf(redm[2], redm[3]));

  float s = 0.f;
#pragma unroll
  for (int i = 0; i < 8; ++i) { v[i] = __expf((v[i] - mx) * SCALE_); s += v[i]; }
  for (int o = 32; o > 0; o >>= 1) s += __shfl_xor(s, o);
  if (lane == 0) reds[wave] = s;
  __syncthreads();
  s = reds[0] + reds[1] + reds[2] + reds[3];
  const float inv = 1.0f / s;
#pragma unroll
  for (int i = 0; i < 8; ++i) v[i] *= inv;

  u.x = bfbits(v[0]) | (bfbits(v[1]) << 16);
  u.y = bfbits(v[2]) | (bfbits(v[3]) << 16);
  u.z = bfbits(v[4]) | (bfbits(v[5]) << 16);
  u.w = bfbits(v[6]) | (bfbits(v[7]) << 16);
  p[t] = u;
}

extern "C" void kernel_launch(void* const* d_in, const int* in_sizes, int n_in,
                              void* d_out, int out_size, void* d_ws, size_t ws_size,
                              hipStream_t stream) {
  const float* x1 = (const float*)d_in[0];
  const float* x2 = (const float*)d_in[1];
  const float* x3 = (const float*)d_in[2];
  const float* Wq = (const float*)d_in[3];
  const float* bq = (const float*)d_in[4];
  const float* Wk = (const float*)d_in[5];
  const float* bk = (const float*)d_in[6];
  const float* Wv = (const float*)d_in[7];
  const float* bv = (const float*)d_in[8];
  const float* Wo = (const float*)d_in[9];
  const float* bo = (const float*)d_in[10];

  char* ws = (char*)d_ws;
  bf16_t* xb    = (bf16_t*)(ws + 0);           // 50,331,648 B
  bf16_t* Wqkvt = (bf16_t*)(ws + 50331648);    // 18,874,368 B (3 x (3072,1024))
  bf16_t* Wot   = (bf16_t*)(ws + 69206016);    // 12,582,912 B
  bf16_t* Q     = (bf16_t*)(ws + 81788928);    // 50,331,648 B
  bf16_t* Kb    = (bf16_t*)(ws + 132120576);   // 50,331,648 B
  bf16_t* Vt    = (bf16_t*)(ws + 182452224);   // 50,331,648 B (total 232,783,872)
  bf16_t* Sc    = (bf16_t*)d_out;              // scores scratch in d_out (100.7 MB)
  bf16_t* ctx   = Q;                           // alias: Q dead after scores GEMM

  // 1) x -> bf16
  cvt_x<<<24576, 256, 0, stream>>>(x1, x2, x3, xb);
  // 2) weights -> bf16 transposed; Wq/Wk/Wv packed into (3072,1024) per m
  transpose_to_bf16<<<dim3(16, 16, 3), 256, 0, stream>>>(Wq, Wqkvt + 0,       1024, 1024, 1048576LL, 3145728LL);
  transpose_to_bf16<<<dim3(16, 16, 3), 256, 0, stream>>>(Wk, Wqkvt + 1048576, 1024, 1024, 1048576LL, 3145728LL);
  transpose_to_bf16<<<dim3(16, 16, 3), 256, 0, stream>>>(Wv, Wqkvt + 2097152, 1024, 1024, 1048576LL, 3145728LL);
  transpose_to_bf16<<<dim3(16, 32, 3), 256, 0, stream>>>(Wo, Wot, 1024, 2048, 2097152LL, 2097152LL);
  // 3) fused QKV projection (+bias); V written transposed (d,t)
  gemm_qkv<<<dim3(24, 64, 3), 256, 0, stream>>>(xb, Wqkvt, bq, bk, bv, Q, Kb, Vt);
  // 4) scores = Q K^T
  gemm_bt_bf16<<<dim3(16, 16, 12), 256, 0, stream>>>(Q, 2097152LL, Dsz, Kb, 2097152LL, Dsz, Sc, 4194304LL, Ssz, Dsz, 0);
  // 5) softmax rows (in place)
  softmax_rows<<<24576, 256, 0, stream>>>(Sc);
  // 6) ctx = P @ V_{(m+1)%3}  (B = Vt, already (d,t))
  gemm_bt_bf16<<<dim3(8, 16, 12), 256, 0, stream>>>(Sc, 4194304LL, Ssz, Vt, 2097152LL, Ssz, ctx, 2097152LL, Dsz, Ssz, 1);
  // 7) out = [x|ctx] @ Wo + bo  -> fp32 d_out (out_m and global_feature)
  gemm_out<<<dim3(8, 64, 3), 256, 0, stream>>>(xb, ctx, Wot, bo, (float*)d_out);
}